// Round 1
// 714.267 us; speedup vs baseline: 1.0021x; 1.0021x over previous
//
#include <hip/hip_runtime.h>

// out[b, :] = softmax_c( depth[b,c]*rgb[b,c]/1000 + depth[b,c] + rgb[b,c] )
// where rgb = x[b,0,:], depth = x[b,1,:].  (Analytic collapse of the DS
// combination: e_a = (b1b2 + b1u2 + b2u1)*S1*S2/K = d*r/K + d + r, the
// denom=(1-K) cancels between b_a and S_a, and softmax absorbs the +1.)

constexpr int NUM_CLASSES = 1000;
constexpr int BATCH = 65536;          // fixed problem shape (reference hard-codes it)
constexpr int NC4 = NUM_CLASSES / 4;  // 250 float4 per row-stream

typedef float f4 __attribute__((ext_vector_type(4)));

__global__ __launch_bounds__(256) void ds_softmax_kernel(
    const float* __restrict__ x, float* __restrict__ out, int nrows) {
    const int wave = threadIdx.x >> 6;
    const int lane = threadIdx.x & 63;
    const long long row = (long long)blockIdx.x * 4 + wave;
    if (row >= nrows) return;

    const f4* __restrict__ rgb4 = (const f4*)(x + row * (2LL * NUM_CLASSES));
    const f4* __restrict__ dep4 = rgb4 + NC4;           // depth follows rgb in-row
    f4* __restrict__ out4 = (f4*)(out + row * (long long)NUM_CLASSES);

    f4 e[4];
    float sum = 0.0f;
#pragma unroll
    for (int j = 0; j < 4; ++j) {
        const int idx = j * 64 + lane;  // 0..255, valid when < 250
        if (idx < NC4) {
            f4 r = __builtin_nontemporal_load(&rgb4[idx]);
            f4 d = __builtin_nontemporal_load(&dep4[idx]);
            // alpha = d*r/1000 + d + r   (softmax shift-invariant: +1 dropped)
            f4 a;
            a.x = fmaf(d.x * r.x, 1.0e-3f, d.x + r.x);
            a.y = fmaf(d.y * r.y, 1.0e-3f, d.y + r.y);
            a.z = fmaf(d.z * r.z, 1.0e-3f, d.z + r.z);
            a.w = fmaf(d.w * r.w, 1.0e-3f, d.w + r.w);
            e[j].x = __expf(a.x);
            e[j].y = __expf(a.y);
            e[j].z = __expf(a.z);
            e[j].w = __expf(a.w);
            sum += (e[j].x + e[j].y) + (e[j].z + e[j].w);
        }
    }

    // 64-lane butterfly reduction (wave = 64 on gfx950)
#pragma unroll
    for (int off = 32; off >= 1; off >>= 1)
        sum += __shfl_xor(sum, off, 64);

    const float inv = 1.0f / sum;

#pragma unroll
    for (int j = 0; j < 4; ++j) {
        const int idx = j * 64 + lane;
        if (idx < NC4) {
            f4 o;
            o.x = e[j].x * inv;
            o.y = e[j].y * inv;
            o.z = e[j].z * inv;
            o.w = e[j].w * inv;
            __builtin_nontemporal_store(o, &out4[idx]);
        }
    }
}

extern "C" void kernel_launch(void* const* d_in, const int* in_sizes, int n_in,
                              void* d_out, int out_size, void* d_ws, size_t ws_size,
                              hipStream_t stream) {
    const float* x = (const float*)d_in[0];
    float* out = (float*)d_out;

    // in_sizes[0] units are ambiguous (elements vs bytes).  The problem shape is
    // fixed at BATCH=65536 rows; both readings collapse to that:
    //   elements: 65536*2*1000     = 131,072,000
    //   bytes:    65536*2*1000*4   = 524,288,000
    // The old code divided by 2000 unconditionally — under the bytes reading that
    // yields nrows=262144 (4x over-dispatch, 3.15 GB of traffic instead of 786 MB).
    int nrows;
    const long long insz = in_sizes[0];
    if (insz == (long long)BATCH * 2 * NUM_CLASSES ||
        insz == (long long)BATCH * 2 * NUM_CLASSES * 4) {
        nrows = BATCH;
    } else {
        // Unknown shape: assume harness byte-count convention (matches out_size/ws_size).
        nrows = (int)(insz / (2LL * NUM_CLASSES * sizeof(float)));
    }

    const int blocks = (nrows + 3) / 4;  // 4 waves/block, 1 row/wave
    ds_softmax_kernel<<<blocks, 256, 0, stream>>>(x, out, nrows);
}